// Round 7
// baseline (1197.179 us; speedup 1.0000x reference)
//
#include <hip/hip_runtime.h>
#include <math.h>

// Vanilla RNN: h_t = tanh(h_{t-1} @ wh + x_t @ wx + b), out = h_T  [B,1,H]
// B=256, T=2048, H=256, fp32 in/out.
//
// Round 6 = round 5 + projection GEMM interleaved INTO the scan:
//  - 256 blocks x 256 threads (4 waves, 1 wave/SIMD, ~512 VGPR budget).
//  - Scan step (serial path): 8 broadcast ds_read_b128 of h + 32 replicated-row
//    MFMA (620cy pipe floor/SIMD) + select + tanh (no clamp: exp(+-inf) gives
//    +-1 exactly) + f16 write + 1 raw s_barrier.
//  - GEMM(c+1) runs 2 MFMA/step AFTER the scan MFMAs (in-order pipe: fills
//    residue, doesn't delay the scan result). xs16/xwc4 double-buffered;
//    x staging for chunk c+2 spread across steps 16-23; chunk boundary is
//    just 8 xwc4 writes + 1 barrier (~200cy vs ~1700 in r5).
//  - Full 32-step unroll: all buffer parities / xr / wfx indices constexpr
//    (rule #20: runtime-indexed ext_vector arrays go to scratch).

typedef _Float16 f16;
typedef _Float16 f16x4 __attribute__((ext_vector_type(4)));
typedef _Float16 f16x8 __attribute__((ext_vector_type(8)));
typedef float    f32x4 __attribute__((ext_vector_type(4)));

#define Bv 256
#define Tv 2048
#define Hv 256
#define TC 32
#define NCHUNK (Tv/TC)
#define XS_LD 264          // f16 row stride (528B -> 2-way banks, free)
#define XW_TS (TC+1)       // ts-dim pad: cq stride 33*16B=528B -> 2-way banks

#define LGKM_BARRIER() do { \
    asm volatile("s_waitcnt lgkmcnt(0)" ::: "memory"); \
    __builtin_amdgcn_s_barrier(); \
} while (0)

#define MFMA16(a, b, c) __builtin_amdgcn_mfma_f32_16x16x32_f16((a), (b), (c), 0, 0, 0)

__device__ __forceinline__ f16x4 cvt4(float4 v) {
    f16x4 r; r[0] = (f16)v.x; r[1] = (f16)v.y; r[2] = (f16)v.z; r[3] = (f16)v.w;
    return r;
}

__global__ __launch_bounds__(256, 1)
void HiddenLayer_704374636647_kernel(const float* __restrict__ x,
                                     const float* __restrict__ wx,
                                     const float* __restrict__ wh,
                                     const float* __restrict__ bias,
                                     float* __restrict__ out)
{
    __shared__ __align__(16) f16   xs16[2][TC][XS_LD];     // 33.8 KB
    __shared__ __align__(16) float xwc4[2][64][XW_TS][4];  // 67.6 KB
    __shared__ __align__(16) f16   hbuf[2][Hv];            //  1.0 KB

    const int  tid   = threadIdx.x;       // 0..255
    const int  wave  = tid >> 6;          // 0..3
    const int  lane  = tid & 63;
    const int  b     = blockIdx.x;
    const int  wbase = wave * 64;         // 64-col slice owned by wave
    const int  l15   = lane & 15;
    const int  grp   = lane >> 4;         // 0..3
    const int  cq    = wave * 16 + l15;   // xwc4 column-quad index
    const int  koff  = grp * 8;           // A-frag k-offset

    const float* xb = x + (size_t)b * Tv * Hv;

    // ---- global x prefetch: 8 rows (wave + 4s) x 4 f32/lane (constexpr-indexed)
    float4 xr[8];
#define LOADX(cc) do { const float* p_ = xb + ((size_t)(cc) * TC + wave) * Hv + lane * 4; \
    _Pragma("unroll") \
    for (int s_ = 0; s_ < 8; ++s_) xr[s_] = *(const float4*)(p_ + (size_t)(4 * s_) * Hv); \
} while (0)

    LOADX(0);

    // ---- weight B-frags: tile t covers col wbase + t*16 + l15; k = kt*32 + koff + e
    f16x8 wfh[4][8];   // wh (recurrence), 128 VGPR
    f16x8 wfx[4][8];   // wx (projection), 128 VGPR
    #pragma unroll
    for (int t = 0; t < 4; ++t) {
        #pragma unroll
        for (int kt = 0; kt < 8; ++kt) {
            const float* ph = wh + (size_t)(kt * 32 + koff) * Hv + wbase + t * 16 + l15;
            const float* pw = wx + (size_t)(kt * 32 + koff) * Hv + wbase + t * 16 + l15;
            f16x8 vh, vw;
            #pragma unroll
            for (int e = 0; e < 8; ++e) {
                vh[e] = (f16)ph[(size_t)e * Hv];
                vw[e] = (f16)pw[(size_t)e * Hv];
            }
            wfh[t][kt] = vh;
            wfx[t][kt] = vw;
        }
    }

    float bcv[4];
    #pragma unroll
    for (int t = 0; t < 4; ++t) bcv[t] = bias[wbase + t * 16 + l15];

    // ---- GEMM accumulators (persist across the scan; constexpr-indexed)
    f32x4 gA[4], gB[4];
#define GINIT() do { _Pragma("unroll") \
    for (int r_ = 0; r_ < 4; ++r_) { \
        f32x4 v_ = {bcv[r_], bcv[r_], bcv[r_], bcv[r_]}; gA[r_] = v_; gB[r_] = v_; } \
} while (0)

#define XWOUT(BUF) do { _Pragma("unroll") \
    for (int rr_ = 0; rr_ < 4; ++rr_) { \
        f32x4 v_ = {gA[0][rr_], gA[1][rr_], gA[2][rr_], gA[3][rr_]}; \
        *(f32x4*)&xwc4[BUF][cq][grp * 4 + rr_][0] = v_; \
        f32x4 w_ = {gB[0][rr_], gB[1][rr_], gB[2][rr_], gB[3][rr_]}; \
        *(f32x4*)&xwc4[BUF][cq][16 + grp * 4 + rr_][0] = w_; } \
} while (0)

#define STAGEX(BUF) do { _Pragma("unroll") \
    for (int s_ = 0; s_ < 8; ++s_) \
        *(f16x4*)&xs16[BUF][wave + 4 * s_][lane * 4] = cvt4(xr[s_]); \
} while (0)

    // ================= PROLOGUE =================
    STAGEX(0);                     // chunk 0 -> xs16[0]
    LOADX(1);
    hbuf[0][tid] = (f16)0.0f;      // h_0 = 0
    LGKM_BARRIER();                // xs16[0] + hbuf visible

    GINIT();
    #pragma unroll
    for (int kt = 0; kt < 8; ++kt) {   // GEMM(0), serial (once)
        f16x8 v0 = *(const f16x8*)&xs16[0][l15     ][kt * 32 + koff];
        f16x8 v1 = *(const f16x8*)&xs16[0][l15 + 16][kt * 32 + koff];
        #pragma unroll
        for (int r = 0; r < 4; ++r) {
            gA[r] = MFMA16(v0, wfx[r][kt], gA[r]);
            gB[r] = MFMA16(v1, wfx[r][kt], gB[r]);
        }
    }
    XWOUT(0);
    GINIT();
    STAGEX(1);                     // chunk 1 -> xs16[1] (vmcnt wait hidden by GEMM)
    LOADX(2);
    LGKM_BARRIER();                // xwc4[0] + xs16[1] visible

    int   cur_par = 0;             // unused; parity is static in the unroll
    (void)cur_par;
    float th_keep = 0.0f;
    f16x8 u0, u1;                  // GEMM A-frags, live across a 4-step quad

    // ---- one scan step (TS = compile-time 0..31)
#define STEP(TS) do { \
    const f16* hp_ = &hbuf[(TS) & 1][koff]; \
    f16x8 ha0 = *(const f16x8*)(hp_); \
    f16x8 ha1 = *(const f16x8*)(hp_ + 32); \
    f16x8 ha2 = *(const f16x8*)(hp_ + 64); \
    f16x8 ha3 = *(const f16x8*)(hp_ + 96); \
    f16x8 ha4 = *(const f16x8*)(hp_ + 128); \
    f16x8 ha5 = *(const f16x8*)(hp_ + 160); \
    f16x8 ha6 = *(const f16x8*)(hp_ + 192); \
    f16x8 ha7 = *(const f16x8*)(hp_ + 224); \
    if constexpr (((TS) & 3) == 0) { \
        constexpr int kt_ = (TS) >> 2; \
        u0 = *(const f16x8*)(xsg + l15 * XS_LD + kt_ * 32 + koff); \
        u1 = *(const f16x8*)(xsg + (l15 + 16) * XS_LD + kt_ * 32 + koff); \
    } \
    float x01_ = (grp & 1) ? xwn[1] : xwn[0]; \
    float x23_ = (grp & 1) ? xwn[3] : xwn[2]; \
    float xws_ = (grp & 2) ? x23_ : x01_; \
    { constexpr int tn_ = ((TS) + 1 < TC) ? (TS) + 1 : (TS); \
      xwn = *(const f32x4*)(seedp + tn_ * 4); } \
    const f32x4 z_ = {0.f, 0.f, 0.f, 0.f}; \
    f32x4 a0A = MFMA16(ha0, wfh[0][0], z_), a0B = MFMA16(ha4, wfh[0][4], z_); \
    f32x4 a1A = MFMA16(ha0, wfh[1][0], z_), a1B = MFMA16(ha4, wfh[1][4], z_); \
    f32x4 a2A = MFMA16(ha0, wfh[2][0], z_), a2B = MFMA16(ha4, wfh[2][4], z_); \
    f32x4 a3A = MFMA16(ha0, wfh[3][0], z_), a3B = MFMA16(ha4, wfh[3][4], z_); \
    a0A = MFMA16(ha1, wfh[0][1], a0A);  a0B = MFMA16(ha5, wfh[0][5], a0B); \
    a1A = MFMA16(ha1, wfh[1][1], a1A);  a1B = MFMA16(ha5, wfh[1][5], a1B); \
    a2A = MFMA16(ha1, wfh[2][1], a2A);  a2B = MFMA16(ha5, wfh[2][5], a2B); \
    a3A = MFMA16(ha1, wfh[3][1], a3A);  a3B = MFMA16(ha5, wfh[3][5], a3B); \
    a0A = MFMA16(ha2, wfh[0][2], a0A);  a0B = MFMA16(ha6, wfh[0][6], a0B); \
    a1A = MFMA16(ha2, wfh[1][2], a1A);  a1B = MFMA16(ha6, wfh[1][6], a1B); \
    a2A = MFMA16(ha2, wfh[2][2], a2A);  a2B = MFMA16(ha6, wfh[2][6], a2B); \
    a3A = MFMA16(ha2, wfh[3][2], a3A);  a3B = MFMA16(ha6, wfh[3][6], a3B); \
    a0A = MFMA16(ha3, wfh[0][3], a0A);  a0B = MFMA16(ha7, wfh[0][7], a0B); \
    a1A = MFMA16(ha3, wfh[1][3], a1A);  a1B = MFMA16(ha7, wfh[1][7], a1B); \
    a2A = MFMA16(ha3, wfh[2][3], a2A);  a2B = MFMA16(ha7, wfh[2][7], a2B); \
    a3A = MFMA16(ha3, wfh[3][3], a3A);  a3B = MFMA16(ha7, wfh[3][7], a3B); \
    { constexpr int kt_ = (TS) >> 2, r_ = (TS) & 3; \
      gA[r_] = MFMA16(u0, wfx[r_][kt_], gA[r_]); \
      gB[r_] = MFMA16(u1, wfx[r_][kt_], gB[r_]); } \
    if constexpr ((TS) >= 16 && (TS) < 24) { \
        constexpr int s_ = (TS) - 16; \
        *(f16x4*)(xst + (wave + 4 * s_) * XS_LD + lane * 4) = cvt4(xr[s_]); \
    } \
    float sA01_ = (grp & 1) ? a1A[0] : a0A[0]; \
    float sA23_ = (grp & 1) ? a3A[0] : a2A[0]; \
    float sA_   = (grp & 2) ? sA23_ : sA01_; \
    float sB01_ = (grp & 1) ? a1B[0] : a0B[0]; \
    float sB23_ = (grp & 1) ? a3B[0] : a2B[0]; \
    float sB_   = (grp & 2) ? sB23_ : sB01_; \
    float s_v   = (sA_ + sB_) + xws_; \
    float e_    = __expf(2.f * s_v); \
    float th_   = 1.f - __fdividef(2.f, e_ + 1.f); \
    th_keep = th_; \
    hbuf[((TS) + 1) & 1][wbase + lane] = (f16)th_; \
    LGKM_BARRIER(); \
} while (0)

    // ================= MAIN LOOP =================
    #pragma unroll 1
    for (int c = 0; c < NCHUNK; ++c) {
        const f16*   xsg   = &xs16[(c + 1) & 1][0][0];   // GEMM(c+1) source
        f16*         xst   = &xs16[c & 1][0][0];         // staging target (chunk c+2)
        const float* seedp = &xwc4[c & 1][cq][0][0];     // scan seeds (chunk c)
        f32x4 xwn = *(const f32x4*)seedp;

        STEP( 0); STEP( 1); STEP( 2); STEP( 3);
        STEP( 4); STEP( 5); STEP( 6); STEP( 7);
        STEP( 8); STEP( 9); STEP(10); STEP(11);
        STEP(12); STEP(13); STEP(14); STEP(15);
        STEP(16); STEP(17); STEP(18); STEP(19);
        STEP(20); STEP(21); STEP(22); STEP(23);
        STEP(24); STEP(25); STEP(26); STEP(27);
        STEP(28); STEP(29); STEP(30); STEP(31);

        // ---- chunk boundary: publish xw(c+1), re-seed accs, next prefetch
        XWOUT((c + 1) & 1);
        GINIT();
        { const int cn = (c + 3 < NCHUNK) ? c + 3 : NCHUNK - 1; LOADX(cn); }
        LGKM_BARRIER();
    }

    // th_keep's col = wbase + lane -> coalesced store
    out[(size_t)b * Hv + wbase + lane] = th_keep;
}

extern "C" void kernel_launch(void* const* d_in, const int* in_sizes, int n_in,
                              void* d_out, int out_size, void* d_ws, size_t ws_size,
                              hipStream_t stream) {
    const float* x    = (const float*)d_in[0];   // [B,T,H]
    const float* wx   = (const float*)d_in[1];   // [H,H]
    const float* wh   = (const float*)d_in[2];   // [H,H]
    const float* bias = (const float*)d_in[3];   // [1,H]
    float* out = (float*)d_out;                  // [B,1,H]

    hipLaunchKernelGGL(HiddenLayer_704374636647_kernel,
                       dim3(Bv), dim3(256), 0, stream,
                       x, wx, wh, bias, out);
}